// Round 2
// baseline (434.284 us; speedup 1.0000x reference)
//
#include <hip/hip_runtime.h>

#define BATCH 65536
#define SEQ   64
#define INF   16
#define HS    10
#define OUTF  5

// Pin a float into a VGPR: opaque to the optimizer -> defeats
// rematerialization/sinking of the originating load into the hot loop.
#define PIN(v) asm volatile("" : "+v"(v))

// One thread per batch row (65536 threads = exactly 1 wave/SIMD, so VGPRs up
// to 512 are free -> hold all 160 W1 weights + state in registers).
__global__ __launch_bounds__(256, 1) void rnn_fused(
    const float* __restrict__ x,  const float* __restrict__ W1,
    const float* __restrict__ b1, const float* __restrict__ W2,
    const float* __restrict__ b2, float* __restrict__ out)
{
    const int b = blockIdx.x * 256 + threadIdx.x;

    // One-time broadcast load of weights, then PIN each value in a VGPR so
    // the compiler cannot re-load them inside the step loop (round-1 failure:
    // VGPR_Count=76 proved w1[] was re-loaded 160x per step from L1).
    float w1[INF * HS];
#pragma unroll
    for (int k = 0; k < INF * HS; ++k) { w1[k] = W1[k]; }
#pragma unroll
    for (int k = 0; k < INF * HS; ++k) { PIN(w1[k]); }

    float bb1[HS];
#pragma unroll
    for (int h = 0; h < HS; ++h) { bb1[h] = b1[h]; }
#pragma unroll
    for (int h = 0; h < HS; ++h) { PIN(bb1[h]); }

    float hreg[HS];
#pragma unroll
    for (int h = 0; h < HS; ++h) hreg[h] = 0.0f;

    const float4* __restrict__ xr =
        reinterpret_cast<const float4*>(x + (size_t)b * (SEQ * INF));

    // depth-4 prefetch pipeline: rows s..s+3 resident (16 KB in flight/wave)
    float4 buf[4][4];
#pragma unroll
    for (int r = 0; r < 4; ++r)
#pragma unroll
        for (int j = 0; j < 4; ++j) buf[r][j] = xr[r * 4 + j];

#pragma unroll 4
    for (int s = 0; s < SEQ; ++s) {
        const int slot = s & 3;
        float xv[INF];
#pragma unroll
        for (int j = 0; j < 4; ++j) {
            xv[j * 4 + 0] = buf[slot][j].x;
            xv[j * 4 + 1] = buf[slot][j].y;
            xv[j * 4 + 2] = buf[slot][j].z;
            xv[j * 4 + 3] = buf[slot][j].w;
        }
        // clamped prefetch (re-reads row 63 near tail: L1 hit, no divergence)
        const int pf = (s + 4 < SEQ) ? (s + 4) : (SEQ - 1);
#pragma unroll
        for (int j = 0; j < 4; ++j) buf[slot][j] = xr[pf * 4 + j];

        float a[HS];
#pragma unroll
        for (int h = 0; h < HS; ++h) a[h] = bb1[h];
#pragma unroll
        for (int i = 0; i < INF; ++i)
#pragma unroll
            for (int h = 0; h < HS; ++h)
                a[h] = fmaf(xv[i], w1[i * HS + h], a[h]);

#pragma unroll
        for (int h = 0; h < HS; ++h) {
            float t = hreg[h] + a[h];
            // tanh(t) = 1 - 2/(exp(2t)+1); rcp ~2-3 ulp, threshold is 1.7e-2
            float e = __expf(2.0f * t);
            hreg[h] = fmaf(-2.0f, __builtin_amdgcn_rcpf(e + 1.0f), 1.0f);
        }
    }

    // epilogue: y = sigmoid(h @ W2 + b2)  (W2/b2 loaded only here)
    float y[OUTF];
#pragma unroll
    for (int o = 0; o < OUTF; ++o) y[o] = b2[o];
#pragma unroll
    for (int h = 0; h < HS; ++h)
#pragma unroll
        for (int o = 0; o < OUTF; ++o)
            y[o] = fmaf(hreg[h], W2[h * OUTF + o], y[o]);

    float* op = out + (size_t)b * OUTF;
#pragma unroll
    for (int o = 0; o < OUTF; ++o)
        op[o] = __builtin_amdgcn_rcpf(1.0f + __expf(-y[o]));
}

extern "C" void kernel_launch(void* const* d_in, const int* in_sizes, int n_in,
                              void* d_out, int out_size, void* d_ws, size_t ws_size,
                              hipStream_t stream) {
    const float* x  = (const float*)d_in[0];
    const float* W1 = (const float*)d_in[1];
    const float* b1 = (const float*)d_in[2];
    const float* W2 = (const float*)d_in[3];
    const float* b2 = (const float*)d_in[4];
    float* out = (float*)d_out;

    rnn_fused<<<BATCH / 256, 256, 0, stream>>>(x, W1, b1, W2, b2, out);
}

// Round 3
// 396.091 us; speedup vs baseline: 1.0964x; 1.0964x over previous
//
#include <hip/hip_runtime.h>

#define BATCH 65536
#define SEQ   64
#define INF   16
#define HS    10
#define OUTF  5

// Pin a float into a VGPR: opaque to the optimizer -> defeats
// rematerialization/sinking of the originating load into the hot loop
// (round-1 lesson: VGPR_Count=76 proved weights were re-loaded per step).
#define PIN(v) asm volatile("" : "+v"(v))

// 4 lanes per batch row (lane j owns input cols 4j..4j+3).
//  - 262144 threads = 4 waves/SIMD (round-2 was 1 wave/SIMD, latency-bound)
//  - one dwordx4 per lane per step; wave = 16 rows x 64B = 16 full lines/instr
//    (round-2: 64 divergent quarter-used lines per instr)
//  - quad all-reduce of the 10 partial activations via __shfl_xor(1),(2);
//    all 4 lanes carry bit-identical h state -> no divergence in the scan.
__global__ __launch_bounds__(256, 4) void rnn_fused(
    const float* __restrict__ x,  const float* __restrict__ W1,
    const float* __restrict__ b1, const float* __restrict__ W2,
    const float* __restrict__ b2, float* __restrict__ out)
{
    const int g   = blockIdx.x * 256 + threadIdx.x;
    const int row = g >> 2;     // batch row
    const int j   = g & 3;      // quad lane: input cols 4j..4j+3

    // Per-lane weight slice: w1l[il*HS+h] = W1[(4j+il)*HS + h]  (40 VGPRs)
    float w1l[4 * HS];
#pragma unroll
    for (int il = 0; il < 4; ++il)
#pragma unroll
        for (int h = 0; h < HS; ++h)
            w1l[il * HS + h] = W1[(4 * j + il) * HS + h];
#pragma unroll
    for (int k = 0; k < 4 * HS; ++k) { PIN(w1l[k]); }

    // quarter-bias: summed over the 4 lanes -> exactly b1[h]
    float bq[HS];
#pragma unroll
    for (int h = 0; h < HS; ++h) { bq[h] = 0.25f * b1[h]; }
#pragma unroll
    for (int h = 0; h < HS; ++h) { PIN(bq[h]); }

    float hreg[HS];
#pragma unroll
    for (int h = 0; h < HS; ++h) hreg[h] = 0.0f;

    // lane j's float4 of step s: x[row][s][4j..4j+3]
    const float4* __restrict__ xr =
        reinterpret_cast<const float4*>(x) + (size_t)row * (SEQ * 4) + j;

    // depth-4 register prefetch (1 KB/wave/slot; 16 waves/CU -> 64 KB in flight)
    float4 buf[4];
#pragma unroll
    for (int r = 0; r < 4; ++r) buf[r] = xr[r * 4];

#pragma unroll 4
    for (int s = 0; s < SEQ; ++s) {
        const int slot = s & 3;
        const float4 xv = buf[slot];
        const int pf = (s + 4 < SEQ) ? (s + 4) : (SEQ - 1);  // clamped: tail re-reads L1
        buf[slot] = xr[pf * 4];

        // partial activation over this lane's 4 inputs
        float a[HS];
#pragma unroll
        for (int h = 0; h < HS; ++h) a[h] = bq[h];
#pragma unroll
        for (int h = 0; h < HS; ++h) {
            a[h] = fmaf(xv.x, w1l[0 * HS + h], a[h]);
            a[h] = fmaf(xv.y, w1l[1 * HS + h], a[h]);
            a[h] = fmaf(xv.z, w1l[2 * HS + h], a[h]);
            a[h] = fmaf(xv.w, w1l[3 * HS + h], a[h]);
        }
        // quad butterfly all-reduce: every lane gets the full sum, bit-identical
#pragma unroll
        for (int h = 0; h < HS; ++h) a[h] += __shfl_xor(a[h], 1);
#pragma unroll
        for (int h = 0; h < HS; ++h) a[h] += __shfl_xor(a[h], 2);

#pragma unroll
        for (int h = 0; h < HS; ++h) {
            float t = hreg[h] + a[h];
            // tanh(t) = 1 - 2/(exp(2t)+1); rcp ~2-3ulp, threshold 1.7e-2
            float e = __expf(2.0f * t);
            hreg[h] = fmaf(-2.0f, __builtin_amdgcn_rcpf(e + 1.0f), 1.0f);
        }
    }

    // epilogue: y = sigmoid(h @ W2 + b2), computed redundantly in the quad
    float y[OUTF];
#pragma unroll
    for (int o = 0; o < OUTF; ++o) y[o] = b2[o];
#pragma unroll
    for (int h = 0; h < HS; ++h)
#pragma unroll
        for (int o = 0; o < OUTF; ++o)
            y[o] = fmaf(hreg[h], W2[h * OUTF + o], y[o]);
#pragma unroll
    for (int o = 0; o < OUTF; ++o)
        y[o] = __builtin_amdgcn_rcpf(1.0f + __expf(-y[o]));

    // lane j writes y[j]; lane 0 also writes y[4]
    float* op = out + (size_t)row * OUTF;
    op[j] = y[j];
    if (j == 0) op[4] = y[4];
}

extern "C" void kernel_launch(void* const* d_in, const int* in_sizes, int n_in,
                              void* d_out, int out_size, void* d_ws, size_t ws_size,
                              hipStream_t stream) {
    const float* x  = (const float*)d_in[0];
    const float* W1 = (const float*)d_in[1];
    const float* b1 = (const float*)d_in[2];
    const float* W2 = (const float*)d_in[3];
    const float* b2 = (const float*)d_in[4];
    float* out = (float*)d_out;

    rnn_fused<<<(BATCH * 4) / 256, 256, 0, stream>>>(x, W1, b1, W2, b2, out);
}

// Round 4
// 380.895 us; speedup vs baseline: 1.1402x; 1.0399x over previous
//
#include <hip/hip_runtime.h>

#define BATCH 65536
#define SEQ   64
#define INF   16
#define HS    10
#define UPL   3     // units per lane (H padded to 12 = 4 lanes * 3)
#define OUTF  5

// Pin a float into a VGPR: opaque to the optimizer -> defeats
// rematerialization/sinking of the originating load into the hot loop.
#define PIN(v) asm volatile("" : "+v"(v))

__device__ __forceinline__ float4 shfl_xor4(float4 v, int m) {
    return make_float4(__shfl_xor(v.x, m), __shfl_xor(v.y, m),
                       __shfl_xor(v.z, m), __shfl_xor(v.w, m));
}

// Quad-per-row, partitioned by HIDDEN UNIT (not by input-column reduce):
//  - lane j loads x cols 4j..4j+3 (wave = 16 rows x 64B full lines, coalesced)
//  - 3 quad shfl_xor broadcasts give every lane all 16 x values; these sit on
//    the feed-forward path, NOT the h_{t-1}->h_t serial chain (round-3 lesson:
//    reduce-shfls on the recurrence chain + 20 trans/step = latency floor)
//  - lane j owns units 3j..3j+2: 48 FMA + only 3 exp + 3 rcp per step,
//    zero redundant tanh work, nothing cross-lane in the recurrence.
__global__ __launch_bounds__(256, 4) void rnn_fused(
    const float* __restrict__ x,  const float* __restrict__ W1,
    const float* __restrict__ b1, const float* __restrict__ W2,
    const float* __restrict__ b2, float* __restrict__ out)
{
    const int g   = blockIdx.x * 256 + threadIdx.x;
    const int row = g >> 2;     // batch row
    const int j   = g & 3;      // quad lane

    // Weights for this lane's units, ordered by shfl-arrival group:
    // group m supplies cols 4*(j^m)+k.  wl[m][k][u] = W1[col][hu], 0-padded
    // for hu>=10 (clamped address, zeroed value).
    float wl[4][4][UPL];
    float bl[UPL];
#pragma unroll
    for (int u = 0; u < UPL; ++u) {
        const int hu = UPL * j + u;
        const int hc = (hu < HS) ? hu : 0;
        const bool ok = (hu < HS);
        bl[u] = ok ? b1[hc] : 0.0f;
#pragma unroll
        for (int m = 0; m < 4; ++m) {
            const int lm = j ^ m;
#pragma unroll
            for (int k = 0; k < 4; ++k) {
                const int col = 4 * lm + k;
                wl[m][k][u] = ok ? W1[col * HS + hc] : 0.0f;
            }
        }
    }
#pragma unroll
    for (int m = 0; m < 4; ++m)
#pragma unroll
        for (int k = 0; k < 4; ++k)
#pragma unroll
            for (int u = 0; u < UPL; ++u) { PIN(wl[m][k][u]); }
#pragma unroll
    for (int u = 0; u < UPL; ++u) { PIN(bl[u]); }

    float h[UPL];
#pragma unroll
    for (int u = 0; u < UPL; ++u) h[u] = 0.0f;

    // lane j's float4 of step s: x[row][s][4j..4j+3]
    const float4* __restrict__ xr =
        reinterpret_cast<const float4*>(x) + (size_t)row * (SEQ * 4) + j;

    // depth-4 register prefetch (1 KB/wave/slot)
    float4 buf[4];
#pragma unroll
    for (int r = 0; r < 4; ++r) buf[r] = xr[r * 4];

#pragma unroll 4
    for (int s = 0; s < SEQ; ++s) {
        const int slot = s & 3;
        const float4 g0 = buf[slot];
        const int pf = (s + 4 < SEQ) ? (s + 4) : (SEQ - 1);  // clamped tail: L1 hit
        buf[slot] = xr[pf * 4];

        // broadcast the quad's 16 x values (feed-forward path only)
        const float4 g1 = shfl_xor4(g0, 1);
        const float4 g2 = shfl_xor4(g0, 2);
        const float4 g3 = shfl_xor4(g0, 3);

#pragma unroll
        for (int u = 0; u < UPL; ++u) {
            // 4 parallel FMA chains (depth 4) -> 2-level tree combine
            float p0 = fmaf(g0.x, wl[0][0][u], bl[u]);
            p0 = fmaf(g0.y, wl[0][1][u], p0);
            p0 = fmaf(g0.z, wl[0][2][u], p0);
            p0 = fmaf(g0.w, wl[0][3][u], p0);
            float p1 = g1.x * wl[1][0][u];
            p1 = fmaf(g1.y, wl[1][1][u], p1);
            p1 = fmaf(g1.z, wl[1][2][u], p1);
            p1 = fmaf(g1.w, wl[1][3][u], p1);
            float p2 = g2.x * wl[2][0][u];
            p2 = fmaf(g2.y, wl[2][1][u], p2);
            p2 = fmaf(g2.z, wl[2][2][u], p2);
            p2 = fmaf(g2.w, wl[2][3][u], p2);
            float p3 = g3.x * wl[3][0][u];
            p3 = fmaf(g3.y, wl[3][1][u], p3);
            p3 = fmaf(g3.z, wl[3][2][u], p3);
            p3 = fmaf(g3.w, wl[3][3][u], p3);
            const float a = (p0 + p1) + (p2 + p3);

            const float t = h[u] + a;
            // tanh(t) = 1 - 2/(exp(2t)+1); rcp ~2-3ulp, threshold 1.7e-2
            const float e = __expf(t + t);
            h[u] = fmaf(-2.0f, __builtin_amdgcn_rcpf(e + 1.0f), 1.0f);
        }
    }

    // epilogue: y = sigmoid(h @ W2 + b2); partial over this lane's units,
    // then quad butterfly all-reduce (padded units have h==0).
    float y[OUTF];
#pragma unroll
    for (int o = 0; o < OUTF; ++o) y[o] = 0.0f;
#pragma unroll
    for (int u = 0; u < UPL; ++u) {
        const int hu = UPL * j + u;
        const float* w2r = W2 + (size_t)((hu < HS) ? hu : 0) * OUTF;
#pragma unroll
        for (int o = 0; o < OUTF; ++o)
            y[o] = fmaf(h[u], w2r[o], y[o]);
    }
#pragma unroll
    for (int o = 0; o < OUTF; ++o) y[o] += __shfl_xor(y[o], 1);
#pragma unroll
    for (int o = 0; o < OUTF; ++o) y[o] += __shfl_xor(y[o], 2);
#pragma unroll
    for (int o = 0; o < OUTF; ++o)
        y[o] = __builtin_amdgcn_rcpf(1.0f + __expf(-(y[o] + b2[o])));

    float* op = out + (size_t)row * OUTF;
    op[j] = y[j];
    if (j == 0) op[4] = y[4];
}

extern "C" void kernel_launch(void* const* d_in, const int* in_sizes, int n_in,
                              void* d_out, int out_size, void* d_ws, size_t ws_size,
                              hipStream_t stream) {
    const float* x  = (const float*)d_in[0];
    const float* W1 = (const float*)d_in[1];
    const float* b1 = (const float*)d_in[2];
    const float* W2 = (const float*)d_in[3];
    const float* b2 = (const float*)d_in[4];
    float* out = (float*)d_out;

    rnn_fused<<<(BATCH * 4) / 256, 256, 0, stream>>>(x, W1, b1, W2, b2, out);
}